// Round 4
// baseline (130.590 us; speedup 1.0000x reference)
//
#include <hip/hip_runtime.h>
#include <hip/hip_bf16.h>

// AdLIF SNN forward, MI355X. B=512, T=500, NIN=96, H=512, NOUT=2.
//
// One block per batch row, 512 threads (8 waves), wave wv owns h in
// [wv*64, wv*64+64). Per 16-step chunk:
//  - x A-fragment loaded straight from global (f32 -> bf16 via
//    __float2bfloat16, NO inline asm), prefetched one chunk ahead;
//    W1 B-fragments persistent in VGPRs.
//  - MFMA swapped operands: D[t][h] (lane: h = lane&15 per tile,
//    t = 4*(lane>>4)+reg) -> I stored bf16 [h][t] (pitch 24 shorts),
//    b64 writes, conflict-free.
//  - Speculative scan: no spike ever => a==0, spk==0, so
//    v = fma(al, v, oma*I); m = max(m, v). Row read = 2x ds_read_b128.
//    m > 1 => flag -> rollback chunk, exact re-run (Wrec path), sticky.
//    Exactness: speculative trajectory equals the true one through the
//    first spike, so the first spike is always detected; the chunk it
//    occurred in is re-run with full AdLIF + recurrence.
// 2 barriers/chunk (64 total).

#define B_ 512
#define T_ 500
#define NIN_ 96
#define H_ 512
#define CH 16
#define NCH 32           // 31 full chunks + 1 partial (4 steps)
#define PT 24            // I_lds row pitch in shorts (48 B)

typedef __attribute__((ext_vector_type(8))) short bf16x8;  // 8 bf16 = 4 VGPR
typedef __attribute__((ext_vector_type(4))) float f32x4;

__device__ __forceinline__ unsigned short f2bf(float f) {
    union { __hip_bfloat16 h; unsigned short s; } u;
    u.h = __float2bfloat16(f);
    return u.s;
}
__device__ __forceinline__ unsigned pk2(float lo, float hi) {
    return (unsigned)f2bf(lo) | ((unsigned)f2bf(hi) << 16);
}
__device__ __forceinline__ float bf_lo(unsigned dw) {
    return __uint_as_float(dw << 16);
}
__device__ __forceinline__ float bf_hi(unsigned dw) {
    return __uint_as_float(dw & 0xffff0000u);
}

// Exact AdLIF steps with recurrent input from spk_lds (cold path).
__device__ __noinline__ void exact_steps(
    int nsteps, const unsigned short* Irow, float* spk_lds,
    const float* __restrict__ Wrec, int tid,
    float al, float oma, float rh, float be,
    float& v, float& a, float& spk)
{
    for (int tt = 0; tt < nsteps; ++tt) {
        float I = __uint_as_float(((unsigned)Irow[tt]) << 16);
        float racc = 0.f;
        for (int hp = 0; hp < H_; ++hp) {
            if (spk_lds[hp] != 0.f) racc += Wrec[(size_t)tid * H_ + hp];
        }
        float vnew = (al * v) * (1.f - spk) + oma * ((I + racc) - a);
        spk = (vnew - 1.f) > 0.f ? 1.f : 0.f;
        a = fmaf(be, spk, rh * a);
        v = vnew;
        __syncthreads();
        spk_lds[tid] = spk;
        __syncthreads();
    }
}

__global__ __launch_bounds__(512, 4) void snn_mfma3(
    const float* __restrict__ x,      // [B, T, NIN]
    const float* __restrict__ W1,     // [H, NIN]
    const float* __restrict__ Wrec,   // [H, H]
    const float* __restrict__ W2,     // [2, H]
    const float* __restrict__ alpha,  // [H]
    const float* __restrict__ rho,    // [H]
    const float* __restrict__ beta_a, // [H]
    float* __restrict__ out)          // [B, 2]
{
    const int b    = blockIdx.x;
    const int tid  = threadIdx.x;
    const int wv   = tid >> 6;
    const int lane = tid & 63;
    const int lq   = lane >> 4;      // k-/t-quad (0..3)
    const int lr   = lane & 15;

    __shared__ unsigned short Ilds[H_ * PT];  // I[h][t] bf16, 24 KB
    __shared__ float spk_lds[H_];
    __shared__ int   flagLds[2];
    __shared__ float red[16];

    // --- W1 B-fragments (persistent): tile i covers h = wv*64+i*16+lr,
    // lane holds k = kb*32 + lq*8 + j.
    bf16x8 wfrag[4][3];
    #pragma unroll
    for (int i = 0; i < 4; ++i) {
        const int h = wv * 64 + i * 16 + lr;
        const float* wrow = W1 + h * NIN_;
        #pragma unroll
        for (int kb = 0; kb < 3; ++kb) {
            const float* p = wrow + kb * 32 + lq * 8;
            float4 u0 = *reinterpret_cast<const float4*>(p);
            float4 u1 = *reinterpret_cast<const float4*>(p + 4);
            union { unsigned d[4]; bf16x8 v8; } pk;
            pk.d[0] = pk2(u0.x, u0.y);
            pk.d[1] = pk2(u0.z, u0.w);
            pk.d[2] = pk2(u1.x, u1.y);
            pk.d[3] = pk2(u1.z, u1.w);
            wfrag[i][kb] = pk.v8;
        }
    }

    const float al  = alpha[tid];
    const float oma = 1.0f - al;
    const float rh  = rho[tid];
    const float be  = beta_a[tid];

    const float* xrow = x + (size_t)b * T_ * NIN_;

    float4 xr[3][2];   // raw f32 x-fragment (prefetch buffer)
    auto LOADX = [&](int c) {
        int t = c * CH + lr;
        t = t < T_ ? t : T_ - 1;               // clamp (last chunk partial)
        const float* p = xrow + t * NIN_ + lq * 8;
        #pragma unroll
        for (int kb = 0; kb < 3; ++kb) {
            xr[kb][0] = *reinterpret_cast<const float4*>(p + kb * 32);
            xr[kb][1] = *reinterpret_cast<const float4*>(p + kb * 32 + 4);
        }
    };

    LOADX(0);
    if (tid == 0) { flagLds[0] = 0; flagLds[1] = 0; }

    float v = 0.f, a = 0.f, spk = 0.f;
    float v0 = 0.f;
    int exactMode = 0;

    for (int c = 0; c < NCH; ++c) {
        __syncthreads();   // S(c): scan(c-1) done, flag(c-1) visible

        // Validate chunk c-1 speculation (I_lds still holds chunk c-1).
        if (c > 0 && !exactMode && flagLds[(c - 1) & 1]) {  // block-uniform
            v = v0; a = 0.f; spk = 0.f;
            spk_lds[tid] = 0.f;
            __syncthreads();
            exact_steps(CH, &Ilds[tid * PT], spk_lds, Wrec,
                        tid, al, oma, rh, be, v, a, spk);
            exactMode = 1;
        }
        v0 = v;   // checkpoint (speculative rollback target)

        // Convert this chunk's x fragment, then prefetch next chunk.
        bf16x8 xf[3];
        #pragma unroll
        for (int kb = 0; kb < 3; ++kb) {
            union { unsigned d[4]; bf16x8 v8; } pk;
            pk.d[0] = pk2(xr[kb][0].x, xr[kb][0].y);
            pk.d[1] = pk2(xr[kb][0].z, xr[kb][0].w);
            pk.d[2] = pk2(xr[kb][1].x, xr[kb][1].y);
            pk.d[3] = pk2(xr[kb][1].z, xr[kb][1].w);
            xf[kb] = pk.v8;
        }
        if (c + 1 < NCH) LOADX(c + 1);          // in flight through the scan
        if (tid == 0) flagLds[c & 1] = 0;       // slot for THIS chunk's flag

        // MFMA, swapped operands: D[t][h].
        f32x4 acc[4] = {{0.f,0.f,0.f,0.f},{0.f,0.f,0.f,0.f},
                        {0.f,0.f,0.f,0.f},{0.f,0.f,0.f,0.f}};
        #pragma unroll
        for (int kb = 0; kb < 3; ++kb)
            #pragma unroll
            for (int i = 0; i < 4; ++i)
                acc[i] = __builtin_amdgcn_mfma_f32_16x16x32_bf16(
                    xf[kb], wfrag[i][kb], acc[i], 0, 0, 0);

        // Store I[h][t] as bf16: lane has t = 4*lq + reg for h = tile col lr.
        #pragma unroll
        for (int i = 0; i < 4; ++i) {
            const int h = wv * 64 + i * 16 + lr;
            uint2 w;
            w.x = pk2(acc[i][0], acc[i][1]);
            w.y = pk2(acc[i][2], acc[i][3]);
            *reinterpret_cast<uint2*>(&Ilds[h * PT + lq * 4]) = w;
        }

        __syncthreads();   // E(c): I_lds(c) visible

        const int steps = (c == NCH - 1) ? (T_ - (NCH - 1) * CH) : CH;

        if (!exactMode) {
            // Speculative scan: a==0, spk==0 => v = fma(al, v, oma*I).
            uint4 ra = *reinterpret_cast<const uint4*>(&Ilds[tid * PT]);
            float m = 0.f;
            #define U2(dw) { \
                v = fmaf(al, v, oma * bf_lo(dw)); m = fmaxf(m, v); \
                v = fmaf(al, v, oma * bf_hi(dw)); m = fmaxf(m, v); }
            if (steps == CH) {
                uint4 rb = *reinterpret_cast<const uint4*>(&Ilds[tid * PT + 8]);
                U2(ra.x) U2(ra.y) U2(ra.z) U2(ra.w)
                U2(rb.x) U2(rb.y) U2(rb.z) U2(rb.w)
            } else {       // last chunk: 4 steps = 2 dwords
                U2(ra.x) U2(ra.y)
            }
            #undef U2
            if (m > 1.f) flagLds[c & 1] = 1;   // benign race, all store 1
        } else {
            exact_steps(steps, &Ilds[tid * PT], spk_lds, Wrec,
                        tid, al, oma, rh, be, v, a, spk);
        }
    }

    // Epilogue: validate the last chunk's speculation.
    __syncthreads();
    if (!exactMode && flagLds[(NCH - 1) & 1]) {
        v = v0; a = 0.f; spk = 0.f;
        spk_lds[tid] = 0.f;
        __syncthreads();
        exact_steps(T_ - (NCH - 1) * CH, &Ilds[tid * PT], spk_lds, Wrec,
                    tid, al, oma, rh, be, v, a, spk);
    }

    // Readout: out[b,n] = sum_h v_h * W2[n,h]
    float p0 = v * W2[tid];
    float p1 = v * W2[H_ + tid];
    #pragma unroll
    for (int off = 32; off > 0; off >>= 1) {
        p0 += __shfl_down(p0, off, 64);
        p1 += __shfl_down(p1, off, 64);
    }
    if (lane == 0) { red[wv * 2] = p0; red[wv * 2 + 1] = p1; }
    __syncthreads();
    if (tid == 0) {
        float s0 = 0.f, s1 = 0.f;
        #pragma unroll
        for (int w8 = 0; w8 < 8; ++w8) { s0 += red[w8 * 2]; s1 += red[w8 * 2 + 1]; }
        out[b * 2 + 0] = s0;
        out[b * 2 + 1] = s1;
    }
}

extern "C" void kernel_launch(void* const* d_in, const int* in_sizes, int n_in,
                              void* d_out, int out_size, void* d_ws, size_t ws_size,
                              hipStream_t stream) {
    const float* x      = (const float*)d_in[0];
    const float* W1     = (const float*)d_in[1];
    const float* Wrec   = (const float*)d_in[2];
    const float* W2     = (const float*)d_in[3];
    const float* alpha  = (const float*)d_in[4];
    const float* rho    = (const float*)d_in[5];
    const float* beta_a = (const float*)d_in[6];
    float* out = (float*)d_out;

    snn_mfma3<<<dim3(B_), dim3(H_), 0, stream>>>(x, W1, Wrec, W2, alpha, rho, beta_a, out);
}

// Round 5
// 54.626 us; speedup vs baseline: 2.3906x; 2.3906x over previous
//
#include <hip/hip_runtime.h>
#include <hip/hip_bf16.h>

// AdLIF SNN forward, MI355X. B=512, T=500, NIN=96, H=512, NOUT=2.
//
// One block per batch row, 512 threads (8 waves), wave wv owns h in
// [wv*64, wv*64+64). Per 16-step chunk:
//  - x chunk staged in LDS as bf16 (shared across all 8 waves; 192 stagers,
//    b128 writes), double-buffered; global loads issued one full chunk early
//    (T14 split: issue-early / write-late).
//  - W1 fragments persistent in registers with oma = (1-alpha) FOLDED IN,
//    so the MFMA produces I' = oma * I directly.
//  - MFMA swapped operands: D[t][h] (lane: h = tile col = lane&15,
//    t = 4*(lane>>4)+reg) -> I' stored bf16 [h][t], pitch 24 shorts.
//    Bank math: b64 store = 4 words/bank (perfect), b128 scan read =
//    8 words/bank (perfect), x-frag b128 read at 208B pitch = 8/bank.
//  - Speculative scan (no spike ever => a==0, spk==0, racc==0):
//    v = fma(al, v, I'); m = max(m, v); m > 1 <=> a spike occurred.
//    Flagged chunk -> rollback (v0 checkpoint; a,spk provably 0) and exact
//    re-run incl. Wrec recurrence, then sticky-exact. The speculative
//    trajectory equals the true one through the first spike, so the first
//    spike is always detected in the chunk it occurs.
// 2 barriers per chunk (64 total).

#define B_ 512
#define T_ 500
#define NIN_ 96
#define H_ 512
#define CH 16
#define NCH 32           // 31 full chunks + 1 partial (4 steps)
#define XPAD 104         // shorts per x row (208 B pitch)
#define PT 24            // shorts per I row (48 B pitch)

typedef __attribute__((ext_vector_type(8))) short bf16x8;  // 8 bf16 = 4 VGPR
typedef __attribute__((ext_vector_type(4))) float f32x4;

__device__ __forceinline__ unsigned short f2bf(float f) {
    union { __hip_bfloat16 h; unsigned short s; } u;
    u.h = __float2bfloat16(f);
    return u.s;
}
__device__ __forceinline__ unsigned pk2(float lo, float hi) {
    return (unsigned)f2bf(lo) | ((unsigned)f2bf(hi) << 16);
}
__device__ __forceinline__ float bf_lo(unsigned dw) {
    return __uint_as_float(dw << 16);
}
__device__ __forceinline__ float bf_hi(unsigned dw) {
    return __uint_as_float(dw & 0xffff0000u);
}

// Exact AdLIF cold path. Irow holds I' = oma*I (bf16, oma-folded).
// vnew = (al*v)*(1-spk) + I' + oma*(racc - a).
__device__ __noinline__ void exact_steps(
    int nsteps, const unsigned short* Irow, float* spk_lds,
    const float* __restrict__ Wrec, int tid,
    float al, float oma, float rh, float be,
    float& v, float& a, float& spk)
{
    for (int tt = 0; tt < nsteps; ++tt) {
        float Ip = __uint_as_float(((unsigned)Irow[tt]) << 16);
        float racc = 0.f;
        for (int hp = 0; hp < H_; ++hp) {
            if (spk_lds[hp] != 0.f) racc += Wrec[(size_t)tid * H_ + hp];
        }
        float vnew = (al * v) * (1.f - spk) + Ip + oma * (racc - a);
        spk = (vnew - 1.f) > 0.f ? 1.f : 0.f;
        a = fmaf(be, spk, rh * a);
        v = vnew;
        __syncthreads();
        spk_lds[tid] = spk;
        __syncthreads();
    }
}

__global__ __launch_bounds__(512, 4) void snn_mfma5(
    const float* __restrict__ x,      // [B, T, NIN]
    const float* __restrict__ W1,     // [H, NIN]
    const float* __restrict__ Wrec,   // [H, H]
    const float* __restrict__ W2,     // [2, H]
    const float* __restrict__ alpha,  // [H]
    const float* __restrict__ rho,    // [H]
    const float* __restrict__ beta_a, // [H]
    float* __restrict__ out)          // [B, 2]
{
    const int b    = blockIdx.x;
    const int tid  = threadIdx.x;
    const int wv   = tid >> 6;
    const int lane = tid & 63;
    const int lq   = lane >> 4;      // k-/t-quad (0..3)
    const int lr   = lane & 15;

    __shared__ __align__(16) unsigned short Ilds[H_ * PT];      // I'[h][t] bf16
    __shared__ __align__(16) unsigned short xlds[2][CH * XPAD]; // x chunk bf16
    __shared__ float spk_lds[H_];
    __shared__ int   flagLds[2];
    __shared__ float red[16];

    // --- W1 fragments (persistent), oma[h] folded in.
    // Tile i covers h = wv*64 + i*16 + lr; lane holds k = kb*32 + lq*8 + j.
    bf16x8 wfrag[4][3];
    #pragma unroll
    for (int i = 0; i < 4; ++i) {
        const int h = wv * 64 + i * 16 + lr;
        const float omaf = 1.0f - alpha[h];
        const float* wrow = W1 + h * NIN_;
        #pragma unroll
        for (int kb = 0; kb < 3; ++kb) {
            const float* p = wrow + kb * 32 + lq * 8;
            float4 u0 = *reinterpret_cast<const float4*>(p);
            float4 u1 = *reinterpret_cast<const float4*>(p + 4);
            union { unsigned d[4]; bf16x8 v8; } pk;
            pk.d[0] = pk2(omaf * u0.x, omaf * u0.y);
            pk.d[1] = pk2(omaf * u0.z, omaf * u0.w);
            pk.d[2] = pk2(omaf * u1.x, omaf * u1.y);
            pk.d[3] = pk2(omaf * u1.z, omaf * u1.w);
            wfrag[i][kb] = pk.v8;
        }
    }

    const float al  = alpha[tid];
    const float oma = 1.0f - al;
    const float rh  = rho[tid];
    const float be  = beta_a[tid];

    // --- x staging: 192 threads, one b128 (8 bf16) each per chunk row-slice.
    const float4* xb4 = reinterpret_cast<const float4*>(x + (size_t)b * T_ * NIN_);
    const int stg = (tid < 192);
    const int st  = tid / 12;        // row t within chunk (0..15)
    const int sq  = tid % 12;        // 16B segment (12 per 96-short row)
    float4 xa = make_float4(0.f,0.f,0.f,0.f), xbv = make_float4(0.f,0.f,0.f,0.f);

    auto XLOAD = [&](int c) {                 // issue global loads (early)
        if (stg) {
            int t = c * CH + st;
            if (t < T_) {
                xa  = xb4[t * 24 + sq * 2];
                xbv = xb4[t * 24 + sq * 2 + 1];
            } else {
                xa = make_float4(0.f,0.f,0.f,0.f);
                xbv = make_float4(0.f,0.f,0.f,0.f);
            }
        }
    };
    auto XWRITE = [&](int c) {                // convert + LDS write (late)
        if (stg) {
            uint4 w;
            w.x = pk2(xa.x, xa.y);  w.y = pk2(xa.z, xa.w);
            w.z = pk2(xbv.x, xbv.y); w.w = pk2(xbv.z, xbv.w);
            *reinterpret_cast<uint4*>(&xlds[c & 1][st * XPAD + sq * 8]) = w;
        }
    };

    XLOAD(0); XWRITE(0);        // chunk 0 synchronously
    XLOAD(1);                   // chunk 1 in flight (consumed end of chunk 0)
    if (tid == 0) { flagLds[0] = 0; flagLds[1] = 0; }

    float v = 0.f, a = 0.f, spk = 0.f;
    float v0 = 0.f;
    int exactMode = 0;

    for (int c = 0; c < NCH; ++c) {
        __syncthreads();   // S(c): xlds[c&1] ready, scan(c-1) + flag visible

        // Validate chunk c-1 speculation (I_lds still holds chunk c-1).
        if (c > 0 && !exactMode && flagLds[(c - 1) & 1]) {  // block-uniform
            v = v0; a = 0.f; spk = 0.f;
            spk_lds[tid] = 0.f;
            __syncthreads();
            exact_steps(CH, &Ilds[tid * PT], spk_lds, Wrec,
                        tid, al, oma, rh, be, v, a, spk);
            exactMode = 1;
        }
        v0 = v;                              // rollback checkpoint
        if (tid == 0) flagLds[c & 1] = 0;    // slot for THIS chunk's flag

        // --- MFMA: I'[t][h] for chunk c. A = x (rows t), B = oma*W1 (cols h).
        f32x4 acc[4] = {{0.f,0.f,0.f,0.f},{0.f,0.f,0.f,0.f},
                        {0.f,0.f,0.f,0.f},{0.f,0.f,0.f,0.f}};
        #pragma unroll
        for (int kb = 0; kb < 3; ++kb) {
            bf16x8 xf = *reinterpret_cast<const bf16x8*>(
                &xlds[c & 1][lr * XPAD + kb * 32 + lq * 8]);
            #pragma unroll
            for (int i = 0; i < 4; ++i)
                acc[i] = __builtin_amdgcn_mfma_f32_16x16x32_bf16(
                    xf, wfrag[i][kb], acc[i], 0, 0, 0);
        }
        // Store I'[h][t] bf16: lane has t = 4*lq + reg for h = wv*64+i*16+lr.
        #pragma unroll
        for (int i = 0; i < 4; ++i) {
            const int h = wv * 64 + i * 16 + lr;
            uint2 w;
            w.x = pk2(acc[i][0], acc[i][1]);
            w.y = pk2(acc[i][2], acc[i][3]);
            *reinterpret_cast<uint2*>(&Ilds[h * PT + lq * 4]) = w;
        }

        if (c + 1 < NCH) XWRITE(c + 1);   // loads from chunk c-1 have landed
        if (c + 2 < NCH) XLOAD(c + 2);    // issue next (consumed next chunk)

        __syncthreads();   // E(c): I_lds(c) + xlds[(c+1)&1] ready

        const int steps = (c == NCH - 1) ? (T_ - (NCH - 1) * CH) : CH;

        if (!exactMode) {
            // Speculative scan: v = fma(al, v, I'); m tracks max(vnew).
            uint4 ra = *reinterpret_cast<const uint4*>(&Ilds[tid * PT]);
            float m = 0.f;
            #define U2(dw) { \
                v = fmaf(al, v, bf_lo(dw)); m = fmaxf(m, v); \
                v = fmaf(al, v, bf_hi(dw)); m = fmaxf(m, v); }
            if (steps == CH) {
                uint4 rb = *reinterpret_cast<const uint4*>(&Ilds[tid * PT + 8]);
                U2(ra.x) U2(ra.y) U2(ra.z) U2(ra.w)
                U2(rb.x) U2(rb.y) U2(rb.z) U2(rb.w)
            } else {       // last chunk: 4 steps = 2 dwords
                U2(ra.x) U2(ra.y)
            }
            #undef U2
            if (m > 1.f) flagLds[c & 1] = 1;   // benign race, all store 1
        } else {
            exact_steps(steps, &Ilds[tid * PT], spk_lds, Wrec,
                        tid, al, oma, rh, be, v, a, spk);
        }
    }

    // Epilogue: validate the last chunk's speculation.
    __syncthreads();
    if (!exactMode && flagLds[(NCH - 1) & 1]) {
        v = v0; a = 0.f; spk = 0.f;
        spk_lds[tid] = 0.f;
        __syncthreads();
        exact_steps(T_ - (NCH - 1) * CH, &Ilds[tid * PT], spk_lds, Wrec,
                    tid, al, oma, rh, be, v, a, spk);
    }

    // Readout: out[b,n] = sum_h v_h * W2[n,h]
    float p0 = v * W2[tid];
    float p1 = v * W2[H_ + tid];
    #pragma unroll
    for (int off = 32; off > 0; off >>= 1) {
        p0 += __shfl_down(p0, off, 64);
        p1 += __shfl_down(p1, off, 64);
    }
    if (lane == 0) { red[wv * 2] = p0; red[wv * 2 + 1] = p1; }
    __syncthreads();
    if (tid == 0) {
        float s0 = 0.f, s1 = 0.f;
        #pragma unroll
        for (int w8 = 0; w8 < 8; ++w8) { s0 += red[w8 * 2]; s1 += red[w8 * 2 + 1]; }
        out[b * 2 + 0] = s0;
        out[b * 2 + 1] = s1;
    }
}

extern "C" void kernel_launch(void* const* d_in, const int* in_sizes, int n_in,
                              void* d_out, int out_size, void* d_ws, size_t ws_size,
                              hipStream_t stream) {
    const float* x      = (const float*)d_in[0];
    const float* W1     = (const float*)d_in[1];
    const float* Wrec   = (const float*)d_in[2];
    const float* W2     = (const float*)d_in[3];
    const float* alpha  = (const float*)d_in[4];
    const float* rho    = (const float*)d_in[5];
    const float* beta_a = (const float*)d_in[6];
    float* out = (float*)d_out;

    snn_mfma5<<<dim3(B_), dim3(H_), 0, stream>>>(x, W1, Wrec, W2, alpha, rho, beta_a, out);
}